// Round 1
// baseline (1512.721 us; speedup 1.0000x reference)
//
#include <hip/hip_runtime.h>

#define NN   50000
#define NE   800000
#define IND  256
#define HIDD 64
#define OUTD 64
#define NH1  4
#define NH2  1
#define NEG  0.2f

// ---- ordered-float trick for atomicMax on float ----
__device__ __forceinline__ unsigned f2o(float f) {
    unsigned u = __float_as_uint(f);
    return (u & 0x80000000u) ? ~u : (u | 0x80000000u);
}
__device__ __forceinline__ float o2f(unsigned o) {
    unsigned u = (o & 0x80000000u) ? (o & 0x7fffffffu) : ~o;
    return __uint_as_float(u);
}

// ---- naive 16x16 smem-tiled fp32 GEMM: C[M,Ncol] = A[M,K] @ B[K,Ncol] ----
// M % 16 == 0, Ncol % 16 == 0, K % 16 == 0 guaranteed by caller.
__global__ void gemm16(const float* __restrict__ A, const float* __restrict__ B,
                       float* __restrict__ C, int M, int Ncol, int K) {
    __shared__ float As[16][16];
    __shared__ float Bs[16][17];
    int row = blockIdx.y * 16 + threadIdx.y;
    int col = blockIdx.x * 16 + threadIdx.x;
    float acc = 0.f;
    for (int k0 = 0; k0 < K; k0 += 16) {
        As[threadIdx.y][threadIdx.x] = A[(size_t)row * K + k0 + threadIdx.x];
        Bs[threadIdx.y][threadIdx.x] = B[(size_t)(k0 + threadIdx.y) * Ncol + col];
        __syncthreads();
#pragma unroll
        for (int kk = 0; kk < 16; ++kk)
            acc += As[threadIdx.y][kk] * Bs[kk][threadIdx.x];
        __syncthreads();
    }
    C[(size_t)row * Ncol + col] = acc;
}

// ---- per-(node,head) attention halves: el = <feat, al>, er = <feat, ar> ----
// one 64-lane wave per (n,h); D hard-coded 64 (HID == OUT == 64)
__global__ void attn_scores(const float* __restrict__ feat, const float* __restrict__ al,
                            const float* __restrict__ ar, float* __restrict__ el,
                            float* __restrict__ er, int H) {
    int gw   = blockIdx.x * (blockDim.x >> 6) + (threadIdx.x >> 6);
    int lane = threadIdx.x & 63;
    if (gw >= NN * H) return;
    int n = gw / H, h = gw - n * H;
    float v  = feat[(size_t)n * H * 64 + h * 64 + lane];
    float pl = v * al[h * 64 + lane];
    float pr = v * ar[h * 64 + lane];
    for (int off = 32; off > 0; off >>= 1) {
        pl += __shfl_down(pl, off);
        pr += __shfl_down(pr, off);
    }
    if (lane == 0) { el[gw] = pl; er[gw] = pr; }
}

// ---- edge logits + leaky relu + segment max (atomic, ordered uint) ----
__global__ void edge_logits(const float* __restrict__ el, const float* __restrict__ er,
                            const int* __restrict__ src, const int* __restrict__ dst,
                            float* __restrict__ e, unsigned* __restrict__ emax, int H) {
    int i = blockIdx.x * blockDim.x + threadIdx.x;
    if (i >= NE * H) return;
    int edge = i / H, h = i - edge * H;
    int s = src[edge], d = dst[edge];
    float x = el[s * H + h] + er[d * H + h];
    x = (x >= 0.f) ? x : NEG * x;
    e[i] = x;
    atomicMax(&emax[d * H + h], f2o(x));
}

// ---- exp(e - max) and segment sum ----
__global__ void edge_exp(float* __restrict__ e, const unsigned* __restrict__ emax,
                         const int* __restrict__ dst, float* __restrict__ esum, int H) {
    int i = blockIdx.x * blockDim.x + threadIdx.x;
    if (i >= NE * H) return;
    int edge = i / H, h = i - edge * H;
    int d = dst[edge];
    float v = __expf(e[i] - o2f(emax[d * H + h]));
    e[i] = v;
    atomicAdd(&esum[d * H + h], v);
}

// ---- alpha-weighted scatter-add of source features into dst accumulator ----
// H*64 threads per edge; epb edges per 256-thread block
__global__ void scatter_agg(const float* __restrict__ feat, const float* __restrict__ e,
                            const float* __restrict__ esum, const int* __restrict__ src,
                            const int* __restrict__ dst, float* __restrict__ out,
                            int H, int epb) {
    int hd    = H * 64;
    int local = threadIdx.x / hd;
    int t     = threadIdx.x - local * hd;
    int edge  = blockIdx.x * epb + local;
    if (edge >= NE) return;
    int h = t >> 6;
    int s = src[edge], d = dst[edge];
    float alpha = e[edge * H + h] / esum[d * H + h];
    atomicAdd(&out[(size_t)d * hd + t], alpha * feat[(size_t)s * hd + t]);
}

// ---- bias (+optional relu) in place ----
__global__ void bias_act(float* __restrict__ x, const float* __restrict__ b,
                         int HD, int do_relu, size_t total) {
    size_t i = (size_t)blockIdx.x * blockDim.x + threadIdx.x;
    if (i >= total) return;
    int t = (int)(i % HD);
    float v = x[i] + b[t];
    if (do_relu) v = fmaxf(v, 0.f);
    x[i] = v;
}

extern "C" void kernel_launch(void* const* d_in, const int* in_sizes, int n_in,
                              void* d_out, int out_size, void* d_ws, size_t ws_size,
                              hipStream_t stream) {
    const float* features = (const float*)d_in[0];
    const int*   src      = (const int*)  d_in[1];
    const int*   dst      = (const int*)  d_in[2];
    const float* W1       = (const float*)d_in[3];
    const float* al1      = (const float*)d_in[4];
    const float* ar1      = (const float*)d_in[5];
    const float* b1       = (const float*)d_in[6];
    const float* W2       = (const float*)d_in[7];
    const float* al2      = (const float*)d_in[8];
    const float* ar2      = (const float*)d_in[9];
    const float* b2       = (const float*)d_in[10];
    float* out = (float*)d_out;

    // ---- workspace layout (floats) ----
    float* p = (float*)d_ws;
    float*    feat1 = p; p += (size_t)NN * 256;   // 12.8M
    float*    h1    = p; p += (size_t)NN * 256;   // 12.8M
    float*    feat2 = p; p += (size_t)NN * 64;    // 3.2M
    float*    e1    = p; p += (size_t)NE * NH1;   // 3.2M
    float*    e2    = p; p += (size_t)NE;         // 0.8M
    float*    el1   = p; p += (size_t)NN * NH1;
    float*    er1   = p; p += (size_t)NN * NH1;
    unsigned* emax1 = (unsigned*)p; p += (size_t)NN * NH1;
    float*    esum1 = p; p += (size_t)NN * NH1;
    float*    el2   = p; p += NN;
    float*    er2   = p; p += NN;
    unsigned* emax2 = (unsigned*)p; p += NN;
    float*    esum2 = p; p += NN;

    // ---- zero accumulators (every call: ws/out are not re-poisoned) ----
    hipMemsetAsync(h1,    0, (size_t)NN * 256 * 4, stream);
    hipMemsetAsync(emax1, 0, (size_t)NN * NH1 * 4, stream);
    hipMemsetAsync(esum1, 0, (size_t)NN * NH1 * 4, stream);
    hipMemsetAsync(emax2, 0, (size_t)NN * 4, stream);
    hipMemsetAsync(esum2, 0, (size_t)NN * 4, stream);
    hipMemsetAsync(out,   0, (size_t)NN * 64 * 4, stream);

    dim3 b16(16, 16);

    // ======== layer 1 ========
    dim3 g1(IND / 16, NN / 16);
    gemm16<<<g1, b16, 0, stream>>>(features, W1, feat1, NN, IND, IND);

    attn_scores<<<(NN * NH1 + 3) / 4, 256, 0, stream>>>(feat1, al1, ar1, el1, er1, NH1);

    edge_logits<<<(NE * NH1 + 255) / 256, 256, 0, stream>>>(el1, er1, src, dst, e1, emax1, NH1);
    edge_exp   <<<(NE * NH1 + 255) / 256, 256, 0, stream>>>(e1, emax1, dst, esum1, NH1);

    scatter_agg<<<NE, 256, 0, stream>>>(feat1, e1, esum1, src, dst, h1, NH1, 1);

    bias_act<<<(NN * 256 + 255) / 256, 256, 0, stream>>>(h1, b1, 256, 1, (size_t)NN * 256);

    // ======== layer 2 ========
    dim3 g2(OUTD / 16, NN / 16);
    gemm16<<<g2, b16, 0, stream>>>(h1, W2, feat2, NN, OUTD, IND);

    attn_scores<<<(NN * NH2 + 3) / 4, 256, 0, stream>>>(feat2, al2, ar2, el2, er2, NH2);

    edge_logits<<<(NE + 255) / 256, 256, 0, stream>>>(el2, er2, src, dst, e2, emax2, NH2);
    edge_exp   <<<(NE + 255) / 256, 256, 0, stream>>>(e2, emax2, dst, esum2, NH2);

    scatter_agg<<<NE / 4, 256, 0, stream>>>(feat2, e2, esum2, src, dst, out, NH2, 4);

    bias_act<<<(NN * 64 + 255) / 256, 256, 0, stream>>>(out, b2, 64, 0, (size_t)NN * 64);
}

// Round 2
// 574.228 us; speedup vs baseline: 2.6344x; 2.6344x over previous
//
#include <hip/hip_runtime.h>

#define NN   50000
#define NE   800000
#define IND  256
#define HIDD 64
#define OUTD 64
#define NH1  4
#define NH2  1
#define NEG  0.2f

// ================= CSR build =================

__global__ void hist_k(const int* __restrict__ dst, int* __restrict__ deg) {
    int i = blockIdx.x * blockDim.x + threadIdx.x;
    if (i < NE) atomicAdd(&deg[dst[i]], 1);
}

// per-block exclusive scan (Hillis-Steele in LDS), writes block sums
__global__ void scan1_k(const int* __restrict__ in, int* __restrict__ excl,
                        int* __restrict__ bsum, int n) {
    __shared__ int tmp[256];
    int gid = blockIdx.x * 256 + threadIdx.x;
    int v = (gid < n) ? in[gid] : 0;
    tmp[threadIdx.x] = v;
    __syncthreads();
    for (int o = 1; o < 256; o <<= 1) {
        int add = (threadIdx.x >= o) ? tmp[threadIdx.x - o] : 0;
        __syncthreads();
        tmp[threadIdx.x] += add;
        __syncthreads();
    }
    if (gid < n) excl[gid] = tmp[threadIdx.x] - v;
    if (threadIdx.x == 255) bsum[blockIdx.x] = tmp[255];
}

// single-block scan of block sums -> exclusive offsets
__global__ void scan2_k(const int* __restrict__ bsum, int* __restrict__ bofs, int n) {
    __shared__ int tmp[256];
    int v = (threadIdx.x < n) ? bsum[threadIdx.x] : 0;
    tmp[threadIdx.x] = v;
    __syncthreads();
    for (int o = 1; o < 256; o <<= 1) {
        int add = (threadIdx.x >= o) ? tmp[threadIdx.x - o] : 0;
        __syncthreads();
        tmp[threadIdx.x] += add;
        __syncthreads();
    }
    if (threadIdx.x < n) bofs[threadIdx.x] = tmp[threadIdx.x] - v;
}

__global__ void scan3_k(int* __restrict__ off, int* __restrict__ cursor,
                        const int* __restrict__ bofs, int n) {
    int gid = blockIdx.x * 256 + threadIdx.x;
    if (gid >= n) return;
    int v = off[gid] + bofs[blockIdx.x];
    off[gid] = v;
    cursor[gid] = v;
}

__global__ void fill_k(const int* __restrict__ src, const int* __restrict__ dst,
                       int* __restrict__ cursor, int* __restrict__ src_sorted) {
    int i = blockIdx.x * blockDim.x + threadIdx.x;
    if (i >= NE) return;
    int d = dst[i];
    int pos = atomicAdd(&cursor[d], 1);
    src_sorted[pos] = src[i];
}

// ================= GEMM: 64x64 tile, 4x4 per thread, fp32 =================
#define BM 64
#define BN 64
#define BK 16

__global__ void gemm_tile(const float* __restrict__ A, const float* __restrict__ B,
                          float* __restrict__ C, int M, int Ncol, int K) {
    __shared__ float As[BK][BM + 4];   // As[k][m], +4 keeps float-4-ish alignment sane
    __shared__ float Bs[BK][BN];       // Bs[k][n]
    int tx = threadIdx.x & 15, ty = threadIdx.x >> 4;
    int row0 = blockIdx.y * BM, col0 = blockIdx.x * BN;
    float acc[4][4] = {};
    for (int k0 = 0; k0 < K; k0 += BK) {
        {   // A tile: 64 rows x 16 k
            int m  = threadIdx.x >> 2;
            int k4 = (threadIdx.x & 3) * 4;
            int r  = row0 + m;
            float4 v = (r < M) ? *(const float4*)&A[(size_t)r * K + k0 + k4]
                               : make_float4(0.f, 0.f, 0.f, 0.f);
            As[k4 + 0][m] = v.x; As[k4 + 1][m] = v.y;
            As[k4 + 2][m] = v.z; As[k4 + 3][m] = v.w;
        }
        {   // B tile: 16 k x 64 n
            int k  = threadIdx.x >> 4;
            int n4 = (threadIdx.x & 15) * 4;
            *(float4*)&Bs[k][n4] = *(const float4*)&B[(size_t)(k0 + k) * Ncol + col0 + n4];
        }
        __syncthreads();
#pragma unroll
        for (int kk = 0; kk < BK; ++kk) {
            float a[4], b[4];
#pragma unroll
            for (int i = 0; i < 4; ++i) a[i] = As[kk][ty * 4 + i];
#pragma unroll
            for (int j = 0; j < 4; ++j) b[j] = Bs[kk][tx * 4 + j];
#pragma unroll
            for (int i = 0; i < 4; ++i)
#pragma unroll
                for (int j = 0; j < 4; ++j) acc[i][j] += a[i] * b[j];
        }
        __syncthreads();
    }
#pragma unroll
    for (int i = 0; i < 4; ++i) {
        int r = row0 + ty * 4 + i;
        if (r < M) {
            float4 v = make_float4(acc[i][0], acc[i][1], acc[i][2], acc[i][3]);
            *(float4*)&C[(size_t)r * Ncol + col0 + tx * 4] = v;
        }
    }
}

// ================= attention halves =================
// one 64-lane wave per (n,h); D = 64
__global__ void attn_scores(const float* __restrict__ feat, const float* __restrict__ al,
                            const float* __restrict__ ar, float* __restrict__ el,
                            float* __restrict__ er, int H) {
    int gw   = blockIdx.x * (blockDim.x >> 6) + (threadIdx.x >> 6);
    int lane = threadIdx.x & 63;
    if (gw >= NN * H) return;
    int n = gw / H, h = gw - n * H;
    float v  = feat[(size_t)n * H * 64 + h * 64 + lane];
    float pl = v * al[h * 64 + lane];
    float pr = v * ar[h * 64 + lane];
    for (int off = 32; off > 0; off >>= 1) {
        pl += __shfl_down(pl, off);
        pr += __shfl_down(pr, off);
    }
    if (lane == 0) { el[gw] = pl; er[gw] = pr; }
}

// ================= edge softmax per dst node (no atomics) =================
// one wave per dst node; lanes split into H groups of 64/H
__global__ void softmax_csr(const float* __restrict__ el, const float* __restrict__ er,
                            const int* __restrict__ src_sorted, const int* __restrict__ off,
                            const int* __restrict__ deg, float* __restrict__ alpha, int H) {
    int wid  = blockIdx.x * (blockDim.x >> 6) + (threadIdx.x >> 6);
    int lane = threadIdx.x & 63;
    if (wid >= NN) return;
    int d = wid;
    int g = 64 / H;            // lanes per head group
    int h = lane / g;
    int k = lane - h * g;
    int beg = off[d], dg = deg[d];
    if (dg == 0) return;
    float erdh = er[(size_t)d * H + h];

    float xs[4];
    float m = -1e30f;
    int i2 = 0;
    for (int p = k; p < dg; p += g, ++i2) {
        int s = src_sorted[beg + p];
        float x = el[(size_t)s * H + h] + erdh;
        x = (x >= 0.f) ? x : NEG * x;
        if (i2 < 4) xs[i2] = x;
        m = fmaxf(m, x);
    }
    for (int o = g >> 1; o; o >>= 1) m = fmaxf(m, __shfl_xor(m, o));

    float ssum = 0.f;
    i2 = 0;
    for (int p = k; p < dg; p += g, ++i2) {
        float x;
        if (i2 < 4) x = xs[i2];
        else {
            int s = src_sorted[beg + p];
            x = el[(size_t)s * H + h] + erdh;
            x = (x >= 0.f) ? x : NEG * x;
        }
        float ex = __expf(x - m);
        if (i2 < 4) xs[i2] = ex;
        ssum += ex;
    }
    for (int o = g >> 1; o; o >>= 1) ssum += __shfl_xor(ssum, o);
    float inv = 1.f / ssum;

    i2 = 0;
    for (int p = k; p < dg; p += g, ++i2) {
        float ex;
        if (i2 < 4) ex = xs[i2];
        else {
            int s = src_sorted[beg + p];
            float x = el[(size_t)s * H + h] + erdh;
            x = (x >= 0.f) ? x : NEG * x;
            ex = __expf(x - m);
        }
        alpha[(size_t)(beg + p) * H + h] = ex * inv;
    }
}

// ================= aggregation (gather, no atomics) =================
// layer 1: one 256-thread block per dst node; thread t = (h=t>>6, d=t&63)
__global__ void agg_csr_l1(const float* __restrict__ feat, const float* __restrict__ alpha,
                           const int* __restrict__ src_sorted, const int* __restrict__ off,
                           const int* __restrict__ deg, const float* __restrict__ bias,
                           float* __restrict__ out) {
    int d = blockIdx.x;
    int t = threadIdx.x;
    int h = t >> 6;
    int beg = off[d], dg = deg[d];
    float acc = 0.f;
    int   s = (dg > 0) ? src_sorted[beg] : 0;
    float a = (dg > 0) ? alpha[(size_t)beg * 4 + h] : 0.f;
    for (int p = 0; p < dg; ++p) {
        int   s2 = (p + 1 < dg) ? src_sorted[beg + p + 1] : 0;
        float a2 = (p + 1 < dg) ? alpha[(size_t)(beg + p + 1) * 4 + h] : 0.f;
        acc += a * feat[(size_t)s * 256 + t];
        s = s2; a = a2;
    }
    out[(size_t)d * 256 + t] = fmaxf(acc + bias[t], 0.f);
}

// layer 2: one wave per dst node (H=1, D=64), 4 nodes per block
__global__ void agg_csr_l2(const float* __restrict__ feat, const float* __restrict__ alpha,
                           const int* __restrict__ src_sorted, const int* __restrict__ off,
                           const int* __restrict__ deg, const float* __restrict__ bias,
                           float* __restrict__ out) {
    int wid  = blockIdx.x * 4 + (threadIdx.x >> 6);
    int lane = threadIdx.x & 63;
    if (wid >= NN) return;
    int beg = off[wid], dg = deg[wid];
    float acc = 0.f;
    int   s = (dg > 0) ? src_sorted[beg] : 0;
    float a = (dg > 0) ? alpha[beg] : 0.f;
    for (int p = 0; p < dg; ++p) {
        int   s2 = (p + 1 < dg) ? src_sorted[beg + p + 1] : 0;
        float a2 = (p + 1 < dg) ? alpha[beg + p + 1] : 0.f;
        acc += a * feat[(size_t)s * 64 + lane];
        s = s2; a = a2;
    }
    out[(size_t)wid * 64 + lane] = acc + bias[lane];
}

extern "C" void kernel_launch(void* const* d_in, const int* in_sizes, int n_in,
                              void* d_out, int out_size, void* d_ws, size_t ws_size,
                              hipStream_t stream) {
    const float* features = (const float*)d_in[0];
    const int*   src      = (const int*)  d_in[1];
    const int*   dst      = (const int*)  d_in[2];
    const float* W1       = (const float*)d_in[3];
    const float* al1      = (const float*)d_in[4];
    const float* ar1      = (const float*)d_in[5];
    const float* b1       = (const float*)d_in[6];
    const float* W2       = (const float*)d_in[7];
    const float* al2      = (const float*)d_in[8];
    const float* ar2      = (const float*)d_in[9];
    const float* b2       = (const float*)d_in[10];
    float* out = (float*)d_out;

    // ---- workspace layout ----
    float* p = (float*)d_ws;
    float* feat1 = p; p += (size_t)NN * 256;      // also reused as feat2 (NN*64)
    float* h1    = p; p += (size_t)NN * 256;
    float* alpha1 = p; p += (size_t)NE * NH1;     // also reused as alpha2 (NE)
    float* el1 = p; p += (size_t)NN * NH1;
    float* er1 = p; p += (size_t)NN * NH1;
    float* el2 = p; p += NN;
    float* er2 = p; p += NN;
    int* ip = (int*)p;
    int* deg        = ip; ip += NN;
    int* off        = ip; ip += NN;
    int* cursor     = ip; ip += NN;
    int* src_sorted = ip; ip += NE;
    int* bsum       = ip; ip += 256;
    int* bofs       = ip; ip += 256;

    float* feat2  = feat1;   // alias: feat1 dead after agg_csr_l1
    float* alpha2 = alpha1;  // alias: alpha1 dead after agg_csr_l1

    const int NB1 = (NN + 255) / 256;   // 196

    // ---- CSR build (shared by both layers) ----
    hipMemsetAsync(deg, 0, (size_t)NN * 4, stream);
    hist_k <<<(NE + 255) / 256, 256, 0, stream>>>(dst, deg);
    scan1_k<<<NB1, 256, 0, stream>>>(deg, off, bsum, NN);
    scan2_k<<<1, 256, 0, stream>>>(bsum, bofs, NB1);
    scan3_k<<<NB1, 256, 0, stream>>>(off, cursor, bofs, NN);
    fill_k <<<(NE + 255) / 256, 256, 0, stream>>>(src, dst, cursor, src_sorted);

    // ======== layer 1 ========
    {
        dim3 g((IND + BN - 1) / BN, (NN + BM - 1) / BM);
        gemm_tile<<<g, 256, 0, stream>>>(features, W1, feat1, NN, IND, IND);
    }
    attn_scores<<<(NN * NH1 + 3) / 4, 256, 0, stream>>>(feat1, al1, ar1, el1, er1, NH1);
    softmax_csr<<<(NN + 3) / 4, 256, 0, stream>>>(el1, er1, src_sorted, off, deg, alpha1, NH1);
    agg_csr_l1 <<<NN, 256, 0, stream>>>(feat1, alpha1, src_sorted, off, deg, b1, h1);

    // ======== layer 2 ========
    {
        dim3 g((OUTD + BN - 1) / BN, (NN + BM - 1) / BM);
        gemm_tile<<<g, 256, 0, stream>>>(h1, W2, feat2, NN, OUTD, IND);
    }
    attn_scores<<<(NN * NH2 + 3) / 4, 256, 0, stream>>>(feat2, al2, ar2, el2, er2, NH2);
    softmax_csr<<<(NN + 3) / 4, 256, 0, stream>>>(el2, er2, src_sorted, off, deg, alpha2, NH2);
    agg_csr_l2 <<<(NN + 3) / 4, 256, 0, stream>>>(feat2, alpha2, src_sorted, off, deg, b2, out);
}

// Round 3
// 442.772 us; speedup vs baseline: 3.4165x; 1.2969x over previous
//
#include <hip/hip_runtime.h>
#include <hip/hip_fp16.h>

#define NN   50000
#define NE   800000
#define IND  256
#define HIDD 64
#define OUTD 64
#define NH1  4
#define NH2  1
#define NEG  0.2f

// ================= CSR build =================

__global__ void hist_k(const int* __restrict__ dst, int* __restrict__ deg) {
    int i = blockIdx.x * blockDim.x + threadIdx.x;
    if (i < NE) atomicAdd(&deg[dst[i]], 1);
}

__global__ void scan1_k(const int* __restrict__ in, int* __restrict__ excl,
                        int* __restrict__ bsum, int n) {
    __shared__ int tmp[256];
    int gid = blockIdx.x * 256 + threadIdx.x;
    int v = (gid < n) ? in[gid] : 0;
    tmp[threadIdx.x] = v;
    __syncthreads();
    for (int o = 1; o < 256; o <<= 1) {
        int add = (threadIdx.x >= o) ? tmp[threadIdx.x - o] : 0;
        __syncthreads();
        tmp[threadIdx.x] += add;
        __syncthreads();
    }
    if (gid < n) excl[gid] = tmp[threadIdx.x] - v;
    if (threadIdx.x == 255) bsum[blockIdx.x] = tmp[255];
}

__global__ void scan2_k(const int* __restrict__ bsum, int* __restrict__ bofs, int n) {
    __shared__ int tmp[256];
    int v = (threadIdx.x < n) ? bsum[threadIdx.x] : 0;
    tmp[threadIdx.x] = v;
    __syncthreads();
    for (int o = 1; o < 256; o <<= 1) {
        int add = (threadIdx.x >= o) ? tmp[threadIdx.x - o] : 0;
        __syncthreads();
        tmp[threadIdx.x] += add;
        __syncthreads();
    }
    if (threadIdx.x < n) bofs[threadIdx.x] = tmp[threadIdx.x] - v;
}

__global__ void scan3_k(int* __restrict__ off, int* __restrict__ cursor,
                        const int* __restrict__ bofs, int n) {
    int gid = blockIdx.x * 256 + threadIdx.x;
    if (gid >= n) return;
    int v = off[gid] + bofs[blockIdx.x];
    off[gid] = v;
    cursor[gid] = v;
}

__global__ void fill_k(const int* __restrict__ src, const int* __restrict__ dst,
                       int* __restrict__ cursor, int* __restrict__ src_sorted) {
    int i = blockIdx.x * blockDim.x + threadIdx.x;
    if (i >= NE) return;
    int d = dst[i];
    int pos = atomicAdd(&cursor[d], 1);
    src_sorted[pos] = src[i];
}

// ================= GEMM: 128x64 tile, 8x4 per thread, fp32 compute, fp16 out =================
#define BM 128
#define BN 64
#define BK 16

__global__ void gemm_tile(const float* __restrict__ A, const float* __restrict__ B,
                          __half* __restrict__ C, int M, int Ncol, int K) {
    __shared__ float As[BK][BM];   // [k][m]
    __shared__ float Bs[BK][BN];   // [k][n]
    int tx = threadIdx.x & 15;       // 16 col groups of 4
    int ty = threadIdx.x >> 4;       // 16 row groups of 8
    int row0 = blockIdx.y * BM, col0 = blockIdx.x * BN;
    float acc[8][4] = {};
    for (int k0 = 0; k0 < K; k0 += BK) {
        {   // A tile: 128 rows x 16 k; thread -> row = tid>>1, koff = (tid&1)*8
            int m    = threadIdx.x >> 1;
            int koff = (threadIdx.x & 1) * 8;
            int r    = row0 + m;
            float4 v0, v1;
            if (r < M) {
                v0 = *(const float4*)&A[(size_t)r * K + k0 + koff];
                v1 = *(const float4*)&A[(size_t)r * K + k0 + koff + 4];
            } else {
                v0 = make_float4(0.f, 0.f, 0.f, 0.f);
                v1 = v0;
            }
            As[koff + 0][m] = v0.x; As[koff + 1][m] = v0.y;
            As[koff + 2][m] = v0.z; As[koff + 3][m] = v0.w;
            As[koff + 4][m] = v1.x; As[koff + 5][m] = v1.y;
            As[koff + 6][m] = v1.z; As[koff + 7][m] = v1.w;
        }
        {   // B tile: 16 k x 64 n
            int k = threadIdx.x >> 4;
            int n = (threadIdx.x & 15) * 4;
            *(float4*)&Bs[k][n] = *(const float4*)&B[(size_t)(k0 + k) * Ncol + col0 + n];
        }
        __syncthreads();
#pragma unroll
        for (int kk = 0; kk < BK; ++kk) {
            float4 a0 = *(const float4*)&As[kk][ty * 8];
            float4 a1 = *(const float4*)&As[kk][ty * 8 + 4];
            float4 b  = *(const float4*)&Bs[kk][tx * 4];
            float a[8] = {a0.x, a0.y, a0.z, a0.w, a1.x, a1.y, a1.z, a1.w};
            float bb[4] = {b.x, b.y, b.z, b.w};
#pragma unroll
            for (int i = 0; i < 8; ++i)
#pragma unroll
                for (int j = 0; j < 4; ++j) acc[i][j] += a[i] * bb[j];
        }
        __syncthreads();
    }
#pragma unroll
    for (int i = 0; i < 8; ++i) {
        int r = row0 + ty * 8 + i;
        if (r < M) {
            __half2 h01 = __floats2half2_rn(acc[i][0], acc[i][1]);
            __half2 h23 = __floats2half2_rn(acc[i][2], acc[i][3]);
            int2 pk = make_int2(*(int*)&h01, *(int*)&h23);
            *(int2*)&C[(size_t)r * Ncol + col0 + tx * 4] = pk;
        }
    }
}

// ================= attention halves (fp16 feat) =================
__global__ void attn_scores(const __half* __restrict__ feat, const float* __restrict__ al,
                            const float* __restrict__ ar, float* __restrict__ el,
                            float* __restrict__ er, int H) {
    int gw   = blockIdx.x * (blockDim.x >> 6) + (threadIdx.x >> 6);
    int lane = threadIdx.x & 63;
    if (gw >= NN * H) return;
    int n = gw / H, h = gw - n * H;
    float v  = __half2float(feat[(size_t)n * H * 64 + h * 64 + lane]);
    float pl = v * al[h * 64 + lane];
    float pr = v * ar[h * 64 + lane];
    for (int off = 32; off > 0; off >>= 1) {
        pl += __shfl_down(pl, off);
        pr += __shfl_down(pr, off);
    }
    if (lane == 0) { el[gw] = pl; er[gw] = pr; }
}

// ================= edge softmax per dst node (no atomics) =================
__global__ void softmax_csr(const float* __restrict__ el, const float* __restrict__ er,
                            const int* __restrict__ src_sorted, const int* __restrict__ off,
                            const int* __restrict__ deg, float* __restrict__ alpha, int H) {
    int wid  = blockIdx.x * (blockDim.x >> 6) + (threadIdx.x >> 6);
    int lane = threadIdx.x & 63;
    if (wid >= NN) return;
    int d = wid;
    int g = 64 / H;
    int h = lane / g;
    int k = lane - h * g;
    int beg = off[d], dg = deg[d];
    if (dg == 0) return;
    float erdh = er[(size_t)d * H + h];

    float xs[4];
    float m = -1e30f;
    int i2 = 0;
    for (int p = k; p < dg; p += g, ++i2) {
        int s = src_sorted[beg + p];
        float x = el[(size_t)s * H + h] + erdh;
        x = (x >= 0.f) ? x : NEG * x;
        if (i2 < 4) xs[i2] = x;
        m = fmaxf(m, x);
    }
    for (int o = g >> 1; o; o >>= 1) m = fmaxf(m, __shfl_xor(m, o));

    float ssum = 0.f;
    i2 = 0;
    for (int p = k; p < dg; p += g, ++i2) {
        float x;
        if (i2 < 4) x = xs[i2];
        else {
            int s = src_sorted[beg + p];
            x = el[(size_t)s * H + h] + erdh;
            x = (x >= 0.f) ? x : NEG * x;
        }
        float ex = __expf(x - m);
        if (i2 < 4) xs[i2] = ex;
        ssum += ex;
    }
    for (int o = g >> 1; o; o >>= 1) ssum += __shfl_xor(ssum, o);
    float inv = 1.f / ssum;

    i2 = 0;
    for (int p = k; p < dg; p += g, ++i2) {
        float ex;
        if (i2 < 4) ex = xs[i2];
        else {
            int s = src_sorted[beg + p];
            float x = el[(size_t)s * H + h] + erdh;
            x = (x >= 0.f) ? x : NEG * x;
            ex = __expf(x - m);
        }
        alpha[(size_t)(beg + p) * H + h] = ex * inv;
    }
}

// ================= aggregation (gather, fp16 feat, 4x unroll) =================
// layer 1: one 256-thread block per dst node; t = h*64 + d
__global__ void agg_csr_l1(const __half* __restrict__ feat, const float* __restrict__ alpha,
                           const int* __restrict__ src_sorted, const int* __restrict__ off,
                           const int* __restrict__ deg, const float* __restrict__ bias,
                           float* __restrict__ out) {
    int d = blockIdx.x;
    int t = threadIdx.x;
    int h = t >> 6;
    int beg = off[d], dg = deg[d];
    float acc = 0.f;
    int p = 0;
    for (; p + 4 <= dg; p += 4) {
        int s0 = src_sorted[beg + p + 0];
        int s1 = src_sorted[beg + p + 1];
        int s2 = src_sorted[beg + p + 2];
        int s3 = src_sorted[beg + p + 3];
        float a0 = alpha[(size_t)(beg + p + 0) * 4 + h];
        float a1 = alpha[(size_t)(beg + p + 1) * 4 + h];
        float a2 = alpha[(size_t)(beg + p + 2) * 4 + h];
        float a3 = alpha[(size_t)(beg + p + 3) * 4 + h];
        float f0 = __half2float(feat[(size_t)s0 * 256 + t]);
        float f1 = __half2float(feat[(size_t)s1 * 256 + t]);
        float f2 = __half2float(feat[(size_t)s2 * 256 + t]);
        float f3 = __half2float(feat[(size_t)s3 * 256 + t]);
        acc += a0 * f0 + a1 * f1 + a2 * f2 + a3 * f3;
    }
    for (; p < dg; ++p) {
        int s = src_sorted[beg + p];
        float a = alpha[(size_t)(beg + p) * 4 + h];
        acc += a * __half2float(feat[(size_t)s * 256 + t]);
    }
    out[(size_t)d * 256 + t] = fmaxf(acc + bias[t], 0.f);
}

// layer 2: one wave per dst node, 4 nodes per block
__global__ void agg_csr_l2(const __half* __restrict__ feat, const float* __restrict__ alpha,
                           const int* __restrict__ src_sorted, const int* __restrict__ off,
                           const int* __restrict__ deg, const float* __restrict__ bias,
                           float* __restrict__ out) {
    int wid  = blockIdx.x * 4 + (threadIdx.x >> 6);
    int lane = threadIdx.x & 63;
    if (wid >= NN) return;
    int beg = off[wid], dg = deg[wid];
    float acc = 0.f;
    int p = 0;
    for (; p + 4 <= dg; p += 4) {
        int s0 = src_sorted[beg + p + 0];
        int s1 = src_sorted[beg + p + 1];
        int s2 = src_sorted[beg + p + 2];
        int s3 = src_sorted[beg + p + 3];
        float a0 = alpha[beg + p + 0];
        float a1 = alpha[beg + p + 1];
        float a2 = alpha[beg + p + 2];
        float a3 = alpha[beg + p + 3];
        float f0 = __half2float(feat[(size_t)s0 * 64 + lane]);
        float f1 = __half2float(feat[(size_t)s1 * 64 + lane]);
        float f2 = __half2float(feat[(size_t)s2 * 64 + lane]);
        float f3 = __half2float(feat[(size_t)s3 * 64 + lane]);
        acc += a0 * f0 + a1 * f1 + a2 * f2 + a3 * f3;
    }
    for (; p < dg; ++p) {
        int s = src_sorted[beg + p];
        acc += alpha[beg + p] * __half2float(feat[(size_t)s * 64 + lane]);
    }
    out[(size_t)wid * 64 + lane] = acc + bias[lane];
}

extern "C" void kernel_launch(void* const* d_in, const int* in_sizes, int n_in,
                              void* d_out, int out_size, void* d_ws, size_t ws_size,
                              hipStream_t stream) {
    const float* features = (const float*)d_in[0];
    const int*   src      = (const int*)  d_in[1];
    const int*   dst      = (const int*)  d_in[2];
    const float* W1       = (const float*)d_in[3];
    const float* al1      = (const float*)d_in[4];
    const float* ar1      = (const float*)d_in[5];
    const float* b1       = (const float*)d_in[6];
    const float* W2       = (const float*)d_in[7];
    const float* al2      = (const float*)d_in[8];
    const float* ar2      = (const float*)d_in[9];
    const float* b2       = (const float*)d_in[10];
    float* out = (float*)d_out;

    // ---- workspace layout ----
    float* p = (float*)d_ws;
    __half* feat1h = (__half*)p; p += (size_t)NN * 128;   // NN*256 halves
    float*  h1     = p; p += (size_t)NN * 256;
    float*  alpha1 = p; p += (size_t)NE * NH1;
    float*  el1 = p; p += (size_t)NN * NH1;
    float*  er1 = p; p += (size_t)NN * NH1;
    float*  el2 = p; p += NN;
    float*  er2 = p; p += NN;
    int* ip = (int*)p;
    int* deg        = ip; ip += NN;
    int* off        = ip; ip += NN;
    int* cursor     = ip; ip += NN;
    int* src_sorted = ip; ip += NE;
    int* bsum       = ip; ip += 256;
    int* bofs       = ip; ip += 256;

    __half* feat2h = feat1h;   // alias: layer-1 feat dead after agg_csr_l1
    float*  alpha2 = alpha1;

    const int NB1 = (NN + 255) / 256;

    // ---- CSR build ----
    hipMemsetAsync(deg, 0, (size_t)NN * 4, stream);
    hist_k <<<(NE + 255) / 256, 256, 0, stream>>>(dst, deg);
    scan1_k<<<NB1, 256, 0, stream>>>(deg, off, bsum, NN);
    scan2_k<<<1, 256, 0, stream>>>(bsum, bofs, NB1);
    scan3_k<<<NB1, 256, 0, stream>>>(off, cursor, bofs, NN);
    fill_k <<<(NE + 255) / 256, 256, 0, stream>>>(src, dst, cursor, src_sorted);

    // ======== layer 1 ========
    {
        dim3 g(IND / BN, (NN + BM - 1) / BM);
        gemm_tile<<<g, 256, 0, stream>>>(features, W1, feat1h, NN, IND, IND);
    }
    attn_scores<<<(NN * NH1 + 3) / 4, 256, 0, stream>>>(feat1h, al1, ar1, el1, er1, NH1);
    softmax_csr<<<(NN + 3) / 4, 256, 0, stream>>>(el1, er1, src_sorted, off, deg, alpha1, NH1);
    agg_csr_l1 <<<NN, 256, 0, stream>>>(feat1h, alpha1, src_sorted, off, deg, b1, h1);

    // ======== layer 2 ========
    {
        dim3 g(OUTD / BN, (NN + BM - 1) / BM);
        gemm_tile<<<g, 256, 0, stream>>>(h1, W2, feat2h, NN, OUTD, IND);
    }
    attn_scores<<<(NN * NH2 + 3) / 4, 256, 0, stream>>>(feat2h, al2, ar2, el2, er2, NH2);
    softmax_csr<<<(NN + 3) / 4, 256, 0, stream>>>(el2, er2, src_sorted, off, deg, alpha2, NH2);
    agg_csr_l2 <<<(NN + 3) / 4, 256, 0, stream>>>(feat2h, alpha2, src_sorted, off, deg, b2, out);
}

// Round 4
// 360.407 us; speedup vs baseline: 4.1973x; 1.2285x over previous
//
#include <hip/hip_runtime.h>
#include <hip/hip_fp16.h>

#define NN   50000
#define NE   800000
#define IND  256
#define HIDD 64
#define OUTD 64
#define NH1  4
#define NH2  1
#define NEG  0.2f

typedef float f32x4 __attribute__((ext_vector_type(4)));
typedef short s16x8 __attribute__((ext_vector_type(8)));

// round-to-nearest-even fp32 -> bf16 (as short), plus residual
__device__ __forceinline__ short bf16_rne(float f) {
    unsigned u = __float_as_uint(f);
    unsigned r = u + 0x7FFFu + ((u >> 16) & 1u);
    return (short)(r >> 16);
}
__device__ __forceinline__ float bf16_tof(short h) {
    unsigned u = ((unsigned)(unsigned short)h) << 16;
    return __uint_as_float(u);
}
__device__ __forceinline__ void split_bf16(float f, short& hi, short& lo) {
    hi = bf16_rne(f);
    lo = bf16_rne(f - bf16_tof(hi));
}

// ================= CSR build =================

__global__ void hist_k(const int* __restrict__ dst, int* __restrict__ deg) {
    int i = blockIdx.x * blockDim.x + threadIdx.x;
    if (i < NE) atomicAdd(&deg[dst[i]], 1);
}

__global__ void scan1_k(const int* __restrict__ in, int* __restrict__ excl,
                        int* __restrict__ bsum, int n) {
    __shared__ int tmp[256];
    int gid = blockIdx.x * 256 + threadIdx.x;
    int v = (gid < n) ? in[gid] : 0;
    tmp[threadIdx.x] = v;
    __syncthreads();
    for (int o = 1; o < 256; o <<= 1) {
        int add = (threadIdx.x >= o) ? tmp[threadIdx.x - o] : 0;
        __syncthreads();
        tmp[threadIdx.x] += add;
        __syncthreads();
    }
    if (gid < n) excl[gid] = tmp[threadIdx.x] - v;
    if (threadIdx.x == 255) bsum[blockIdx.x] = tmp[255];
}

__global__ void scan2_k(const int* __restrict__ bsum, int* __restrict__ bofs, int n) {
    __shared__ int tmp[256];
    int v = (threadIdx.x < n) ? bsum[threadIdx.x] : 0;
    tmp[threadIdx.x] = v;
    __syncthreads();
    for (int o = 1; o < 256; o <<= 1) {
        int add = (threadIdx.x >= o) ? tmp[threadIdx.x - o] : 0;
        __syncthreads();
        tmp[threadIdx.x] += add;
        __syncthreads();
    }
    if (threadIdx.x < n) bofs[threadIdx.x] = tmp[threadIdx.x] - v;
}

__global__ void scan3_k(int* __restrict__ off, int* __restrict__ cursor,
                        const int* __restrict__ bofs, int n) {
    int gid = blockIdx.x * 256 + threadIdx.x;
    if (gid >= n) return;
    int v = off[gid] + bofs[blockIdx.x];
    off[gid] = v;
    cursor[gid] = v;
}

__global__ void fill_k(const int* __restrict__ src, const int* __restrict__ dst,
                       int* __restrict__ cursor, int* __restrict__ src_sorted) {
    int i = blockIdx.x * blockDim.x + threadIdx.x;
    if (i >= NE) return;
    int d = dst[i];
    int pos = atomicAdd(&cursor[d], 1);
    src_sorted[pos] = src[i];
}

// ================= W transpose + bf16 split: W[k][n] -> Wt[n][k] hi/lo =================
__global__ void wsplit_k(const float* __restrict__ W, short* __restrict__ Wh,
                         short* __restrict__ Wl, int K, int Ncol) {
    int idx = blockIdx.x * 256 + threadIdx.x;
    if (idx >= K * Ncol) return;
    int k = idx / Ncol, n = idx - k * Ncol;
    short hi, lo;
    split_bf16(W[idx], hi, lo);
    Wh[(size_t)n * K + k] = hi;
    Wl[(size_t)n * K + k] = lo;
}

// ================= MFMA GEMM: C[M,Ncol] = A[M,K] @ B, fp16 out =================
// A fp32 row-major (split to bf16 hi/lo on the fly); B pre-split+transposed [Ncol][K].
// 3-term: Ahi*Bhi + Alo*Bhi + Ahi*Blo. Block tile 128x64, 4 waves (2Mx2N), K-chunk 32.
#define GM 128
#define GN 64
#define GK 32

__global__ __launch_bounds__(256) void gemm_mfma(const float* __restrict__ A,
                                                 const short* __restrict__ Bt_hi,
                                                 const short* __restrict__ Bt_lo,
                                                 __half* __restrict__ C,
                                                 int M, int Ncol, int K) {
    __shared__ short As_hi[GM][40];   // [m][k], pad 32->40 (2-way banks only)
    __shared__ short As_lo[GM][40];
    __shared__ short Bs_hi[GN][40];   // [n][k]
    __shared__ short Bs_lo[GN][40];

    int tid  = threadIdx.x;
    int wid  = tid >> 6, lane = tid & 63;
    int wm   = (wid >> 1) * 64;       // wave row offset in tile
    int wn   = (wid & 1) * 32;        // wave col offset in tile
    int row0 = blockIdx.y * GM, col0 = blockIdx.x * GN;

    int arow = tid >> 1;              // 0..127
    int aseg = (tid & 1) * 16;        // 0 | 16
    int brow = tid >> 2;              // 0..63
    int bseg = (tid & 3) * 8;         // 0|8|16|24

    int mr = lane & 15;
    int kg = (lane >> 4) * 8;

    f32x4 acc[4][2];
#pragma unroll
    for (int i = 0; i < 4; ++i)
#pragma unroll
        for (int j = 0; j < 2; ++j) acc[i][j] = (f32x4)(0.f);

    for (int k0 = 0; k0 < K; k0 += GK) {
        {   // ---- stage A: 128 rows x 32 k, split fp32 -> bf16 hi/lo ----
            int r = row0 + arow;
            float v[16];
            if (r < M) {
                const float* ap = &A[(size_t)r * K + k0 + aseg];
#pragma unroll
                for (int q = 0; q < 4; ++q) {
                    float4 f = *(const float4*)(ap + q * 4);
                    v[q * 4 + 0] = f.x; v[q * 4 + 1] = f.y;
                    v[q * 4 + 2] = f.z; v[q * 4 + 3] = f.w;
                }
            } else {
#pragma unroll
                for (int q = 0; q < 16; ++q) v[q] = 0.f;
            }
            short hi[16], lo[16];
#pragma unroll
            for (int q = 0; q < 16; ++q) split_bf16(v[q], hi[q], lo[q]);
            *(s16x8*)&As_hi[arow][aseg]     = *(s16x8*)&hi[0];
            *(s16x8*)&As_hi[arow][aseg + 8] = *(s16x8*)&hi[8];
            *(s16x8*)&As_lo[arow][aseg]     = *(s16x8*)&lo[0];
            *(s16x8*)&As_lo[arow][aseg + 8] = *(s16x8*)&lo[8];
        }
        {   // ---- stage B: 64 n x 32 k (already split/transposed) ----
            const short* bh = &Bt_hi[(size_t)(col0 + brow) * K + k0 + bseg];
            const short* bl = &Bt_lo[(size_t)(col0 + brow) * K + k0 + bseg];
            *(s16x8*)&Bs_hi[brow][bseg] = *(const s16x8*)bh;
            *(s16x8*)&Bs_lo[brow][bseg] = *(const s16x8*)bl;
        }
        __syncthreads();

        s16x8 ah[4], alo[4], bh[2], blo[2];
#pragma unroll
        for (int mi = 0; mi < 4; ++mi) {
            ah[mi]  = *(const s16x8*)&As_hi[wm + mi * 16 + mr][kg];
            alo[mi] = *(const s16x8*)&As_lo[wm + mi * 16 + mr][kg];
        }
#pragma unroll
        for (int ni = 0; ni < 2; ++ni) {
            bh[ni]  = *(const s16x8*)&Bs_hi[wn + ni * 16 + mr][kg];
            blo[ni] = *(const s16x8*)&Bs_lo[wn + ni * 16 + mr][kg];
        }
#pragma unroll
        for (int mi = 0; mi < 4; ++mi)
#pragma unroll
            for (int ni = 0; ni < 2; ++ni) {
                acc[mi][ni] = __builtin_amdgcn_mfma_f32_16x16x32_bf16(ah[mi],  bh[ni],  acc[mi][ni], 0, 0, 0);
                acc[mi][ni] = __builtin_amdgcn_mfma_f32_16x16x32_bf16(alo[mi], bh[ni],  acc[mi][ni], 0, 0, 0);
                acc[mi][ni] = __builtin_amdgcn_mfma_f32_16x16x32_bf16(ah[mi],  blo[ni], acc[mi][ni], 0, 0, 0);
            }
        __syncthreads();
    }

    // ---- epilogue: D[row=(lane>>4)*4+r][col=lane&15] ----
#pragma unroll
    for (int mi = 0; mi < 4; ++mi) {
#pragma unroll
        for (int ni = 0; ni < 2; ++ni) {
#pragma unroll
            for (int r4 = 0; r4 < 4; ++r4) {
                int rr = row0 + wm + mi * 16 + (lane >> 4) * 4 + r4;
                int cc = col0 + wn + ni * 16 + (lane & 15);
                if (rr < M) C[(size_t)rr * Ncol + cc] = __float2half(acc[mi][ni][r4]);
            }
        }
    }
}

// ================= attention halves (fp16 feat) =================
__global__ void attn_scores(const __half* __restrict__ feat, const float* __restrict__ al,
                            const float* __restrict__ ar, float* __restrict__ el,
                            float* __restrict__ er, int H) {
    int gw   = blockIdx.x * (blockDim.x >> 6) + (threadIdx.x >> 6);
    int lane = threadIdx.x & 63;
    if (gw >= NN * H) return;
    int n = gw / H, h = gw - n * H;
    float v  = __half2float(feat[(size_t)n * H * 64 + h * 64 + lane]);
    float pl = v * al[h * 64 + lane];
    float pr = v * ar[h * 64 + lane];
    for (int off = 32; off > 0; off >>= 1) {
        pl += __shfl_down(pl, off);
        pr += __shfl_down(pr, off);
    }
    if (lane == 0) { el[gw] = pl; er[gw] = pr; }
}

// ================= edge softmax per dst node =================
__global__ void softmax_csr(const float* __restrict__ el, const float* __restrict__ er,
                            const int* __restrict__ src_sorted, const int* __restrict__ off,
                            const int* __restrict__ deg, float* __restrict__ alpha, int H) {
    int wid  = blockIdx.x * (blockDim.x >> 6) + (threadIdx.x >> 6);
    int lane = threadIdx.x & 63;
    if (wid >= NN) return;
    int d = wid;
    int g = 64 / H;
    int h = lane / g;
    int k = lane - h * g;
    int beg = off[d], dg = deg[d];
    if (dg == 0) return;
    float erdh = er[(size_t)d * H + h];

    float xs[4];
    float m = -1e30f;
    int i2 = 0;
    for (int p = k; p < dg; p += g, ++i2) {
        int s = src_sorted[beg + p];
        float x = el[(size_t)s * H + h] + erdh;
        x = (x >= 0.f) ? x : NEG * x;
        if (i2 < 4) xs[i2] = x;
        m = fmaxf(m, x);
    }
    for (int o = g >> 1; o; o >>= 1) m = fmaxf(m, __shfl_xor(m, o));

    float ssum = 0.f;
    i2 = 0;
    for (int p = k; p < dg; p += g, ++i2) {
        float x;
        if (i2 < 4) x = xs[i2];
        else {
            int s = src_sorted[beg + p];
            x = el[(size_t)s * H + h] + erdh;
            x = (x >= 0.f) ? x : NEG * x;
        }
        float ex = __expf(x - m);
        if (i2 < 4) xs[i2] = ex;
        ssum += ex;
    }
    for (int o = g >> 1; o; o >>= 1) ssum += __shfl_xor(ssum, o);
    float inv = 1.f / ssum;

    i2 = 0;
    for (int p = k; p < dg; p += g, ++i2) {
        float ex;
        if (i2 < 4) ex = xs[i2];
        else {
            int s = src_sorted[beg + p];
            float x = el[(size_t)s * H + h] + erdh;
            x = (x >= 0.f) ? x : NEG * x;
            ex = __expf(x - m);
        }
        alpha[(size_t)(beg + p) * H + h] = ex * inv;
    }
}

// ================= aggregation (gather, fp16 feat, 4x unroll) =================
__global__ void agg_csr_l1(const __half* __restrict__ feat, const float* __restrict__ alpha,
                           const int* __restrict__ src_sorted, const int* __restrict__ off,
                           const int* __restrict__ deg, const float* __restrict__ bias,
                           float* __restrict__ out) {
    int d = blockIdx.x;
    int t = threadIdx.x;
    int h = t >> 6;
    int beg = off[d], dg = deg[d];
    float acc = 0.f;
    int p = 0;
    for (; p + 4 <= dg; p += 4) {
        int s0 = src_sorted[beg + p + 0];
        int s1 = src_sorted[beg + p + 1];
        int s2 = src_sorted[beg + p + 2];
        int s3 = src_sorted[beg + p + 3];
        float a0 = alpha[(size_t)(beg + p + 0) * 4 + h];
        float a1 = alpha[(size_t)(beg + p + 1) * 4 + h];
        float a2 = alpha[(size_t)(beg + p + 2) * 4 + h];
        float a3 = alpha[(size_t)(beg + p + 3) * 4 + h];
        float f0 = __half2float(feat[(size_t)s0 * 256 + t]);
        float f1 = __half2float(feat[(size_t)s1 * 256 + t]);
        float f2 = __half2float(feat[(size_t)s2 * 256 + t]);
        float f3 = __half2float(feat[(size_t)s3 * 256 + t]);
        acc += a0 * f0 + a1 * f1 + a2 * f2 + a3 * f3;
    }
    for (; p < dg; ++p) {
        int s = src_sorted[beg + p];
        float a = alpha[(size_t)(beg + p) * 4 + h];
        acc += a * __half2float(feat[(size_t)s * 256 + t]);
    }
    out[(size_t)d * 256 + t] = fmaxf(acc + bias[t], 0.f);
}

__global__ void agg_csr_l2(const __half* __restrict__ feat, const float* __restrict__ alpha,
                           const int* __restrict__ src_sorted, const int* __restrict__ off,
                           const int* __restrict__ deg, const float* __restrict__ bias,
                           float* __restrict__ out) {
    int wid  = blockIdx.x * 4 + (threadIdx.x >> 6);
    int lane = threadIdx.x & 63;
    if (wid >= NN) return;
    int beg = off[wid], dg = deg[wid];
    float acc = 0.f;
    int p = 0;
    for (; p + 4 <= dg; p += 4) {
        int s0 = src_sorted[beg + p + 0];
        int s1 = src_sorted[beg + p + 1];
        int s2 = src_sorted[beg + p + 2];
        int s3 = src_sorted[beg + p + 3];
        float a0 = alpha[beg + p + 0];
        float a1 = alpha[beg + p + 1];
        float a2 = alpha[beg + p + 2];
        float a3 = alpha[beg + p + 3];
        float f0 = __half2float(feat[(size_t)s0 * 64 + lane]);
        float f1 = __half2float(feat[(size_t)s1 * 64 + lane]);
        float f2 = __half2float(feat[(size_t)s2 * 64 + lane]);
        float f3 = __half2float(feat[(size_t)s3 * 64 + lane]);
        acc += a0 * f0 + a1 * f1 + a2 * f2 + a3 * f3;
    }
    for (; p < dg; ++p) {
        int s = src_sorted[beg + p];
        acc += alpha[beg + p] * __half2float(feat[(size_t)s * 64 + lane]);
    }
    out[(size_t)wid * 64 + lane] = acc + bias[lane];
}

extern "C" void kernel_launch(void* const* d_in, const int* in_sizes, int n_in,
                              void* d_out, int out_size, void* d_ws, size_t ws_size,
                              hipStream_t stream) {
    const float* features = (const float*)d_in[0];
    const int*   src      = (const int*)  d_in[1];
    const int*   dst      = (const int*)  d_in[2];
    const float* W1       = (const float*)d_in[3];
    const float* al1      = (const float*)d_in[4];
    const float* ar1      = (const float*)d_in[5];
    const float* b1       = (const float*)d_in[6];
    const float* W2       = (const float*)d_in[7];
    const float* al2      = (const float*)d_in[8];
    const float* ar2      = (const float*)d_in[9];
    const float* b2       = (const float*)d_in[10];
    float* out = (float*)d_out;

    // ---- workspace layout ----
    float* p = (float*)d_ws;
    __half* feat1h = (__half*)p; p += (size_t)NN * 128;   // NN*256 halves
    float*  h1     = p; p += (size_t)NN * 256;
    float*  alpha1 = p; p += (size_t)NE * NH1;
    float*  el1 = p; p += (size_t)NN * NH1;
    float*  er1 = p; p += (size_t)NN * NH1;
    float*  el2 = p; p += NN;
    float*  er2 = p; p += NN;
    int* ip = (int*)p;
    int* deg        = ip; ip += NN;
    int* off        = ip; ip += NN;
    int* cursor     = ip; ip += NN;
    int* src_sorted = ip; ip += NE;
    int* bsum       = ip; ip += 256;
    int* bofs       = ip; ip += 256;
    short* sp = (short*)ip;
    short* Wt1_hi = sp; sp += (size_t)IND * IND;     // [256][256]
    short* Wt1_lo = sp; sp += (size_t)IND * IND;
    short* Wt2_hi = sp; sp += (size_t)OUTD * IND;    // [64][256]
    short* Wt2_lo = sp; sp += (size_t)OUTD * IND;

    __half* feat2h = feat1h;
    float*  alpha2 = alpha1;

    const int NB1 = (NN + 255) / 256;

    // ---- CSR build ----
    hipMemsetAsync(deg, 0, (size_t)NN * 4, stream);
    hist_k <<<(NE + 255) / 256, 256, 0, stream>>>(dst, deg);
    scan1_k<<<NB1, 256, 0, stream>>>(deg, off, bsum, NN);
    scan2_k<<<1, 256, 0, stream>>>(bsum, bofs, NB1);
    scan3_k<<<NB1, 256, 0, stream>>>(off, cursor, bofs, NN);
    fill_k <<<(NE + 255) / 256, 256, 0, stream>>>(src, dst, cursor, src_sorted);

    // ---- weight transpose + split (both layers) ----
    wsplit_k<<<(IND * IND + 255) / 256, 256, 0, stream>>>(W1, Wt1_hi, Wt1_lo, IND, IND);
    wsplit_k<<<(IND * OUTD + 255) / 256, 256, 0, stream>>>(W2, Wt2_hi, Wt2_lo, IND, OUTD);

    // ======== layer 1 ========
    {
        dim3 g(IND / GN, (NN + GM - 1) / GM);
        gemm_mfma<<<g, 256, 0, stream>>>(features, Wt1_hi, Wt1_lo, feat1h, NN, IND, IND);
    }
    attn_scores<<<(NN * NH1 + 3) / 4, 256, 0, stream>>>(feat1h, al1, ar1, el1, er1, NH1);
    softmax_csr<<<(NN + 3) / 4, 256, 0, stream>>>(el1, er1, src_sorted, off, deg, alpha1, NH1);
    agg_csr_l1 <<<NN, 256, 0, stream>>>(feat1h, alpha1, src_sorted, off, deg, b1, h1);

    // ======== layer 2 ========
    {
        dim3 g(OUTD / GN, (NN + GM - 1) / GM);
        gemm_mfma<<<g, 256, 0, stream>>>(h1, Wt2_hi, Wt2_lo, feat2h, NN, OUTD, IND);
    }
    attn_scores<<<(NN * NH2 + 3) / 4, 256, 0, stream>>>(feat2h, al2, ar2, el2, er2, NH2);
    softmax_csr<<<(NN + 3) / 4, 256, 0, stream>>>(el2, er2, src_sorted, off, deg, alpha2, NH2);
    agg_csr_l2 <<<(NN + 3) / 4, 256, 0, stream>>>(feat2h, alpha2, src_sorted, off, deg, b2, out);
}